// Round 1
// baseline (363.088 us; speedup 1.0000x reference)
//
#include <hip/hip_runtime.h>
#include <hip/hip_bf16.h>
#include <stdint.h>

// Problem constants: B=8, L=512, D=768, W=12
#define L_SEQ   512
#define D_DIM   768
#define W_TAPS  12
#define LPAD    523                    // L + W - 1
#define NROWS   4096                   // B*L
#define MROWS   49152                  // B*L*W
#define XPAD_ELEMS (8 * 523 * 768)     // 3,213,312
#define CWT_KSTRIDE (768 * 768)        // 589,824

typedef __attribute__((ext_vector_type(8))) short bf16x8;
typedef __attribute__((ext_vector_type(4))) float f32x4;

static __device__ __forceinline__ float bf2f(short s) {
    union { uint32_t u; float f; } c;
    c.u = ((uint32_t)(uint16_t)s) << 16;
    return c.f;
}
static __device__ __forceinline__ short f2bf(float f) {
    union { float f; uint32_t u; } c; c.f = f;
    uint32_t u = c.u + 0x7FFFu + ((c.u >> 16) & 1u);   // RNE
    return (short)(u >> 16);
}

// ---- cast + per-batch pad x: [8][512][768] f32 -> [8][523][768] bf16 (pad rows = 0)
__global__ void pad_cast_x(const float* __restrict__ x, __hip_bfloat16* __restrict__ xpad) {
    int i = blockIdx.x * 256 + threadIdx.x;       // float4 groups
    if (i >= XPAD_ELEMS / 4) return;
    int e = i * 4;
    int row = e / 768, col = e % 768;
    int b = row / 523, l = row % 523;
    short4 ov;
    if (l < L_SEQ) {
        const float4* src = (const float4*)&x[((size_t)(b * L_SEQ + l)) * 768 + col];
        float4 v = *src;
        ov.x = f2bf(v.x); ov.y = f2bf(v.y); ov.z = f2bf(v.z); ov.w = f2bf(v.w);
    } else {
        ov.x = 0; ov.y = 0; ov.z = 0; ov.w = 0;
    }
    *(short4*)&xpad[e] = ov;
}

// ---- conv_w [c][d][k] f32 -> cwt [k][c][d] bf16  (contraction d contiguous)
__global__ void transpose_cw(const float* __restrict__ cw, __hip_bfloat16* __restrict__ cwt) {
    int blk = blockIdx.x;              // 768 * 12 = 9216 blocks of 64 threads
    int c = blk / 12;
    int dc = (blk % 12) * 64;
    __shared__ float tile[768];        // 64 d x 12 k, stored input-linear
    int lane = threadIdx.x;
    const float* src = cw + (size_t)c * (768 * 12) + (size_t)dc * 12;
    #pragma unroll
    for (int j = 0; j < 12; ++j) tile[j * 64 + lane] = src[j * 64 + lane];
    __syncthreads();
    #pragma unroll
    for (int k = 0; k < 12; ++k) {
        cwt[(size_t)k * CWT_KSTRIDE + (size_t)c * 768 + dc + lane] =
            __float2bfloat16(tile[lane * 12 + k]);
    }
}

// ---- proj_w f32 -> bf16 (layout kept: [o][d])
__global__ void cast_pw(const float* __restrict__ pw, __hip_bfloat16* __restrict__ pwb) {
    int i = blockIdx.x * 256 + threadIdx.x;       // 147,456 exact
    int e = i * 4;
    float4 v = *(const float4*)&pw[e];
    short4 ov; ov.x = f2bf(v.x); ov.y = f2bf(v.y); ov.z = f2bf(v.z); ov.w = f2bf(v.w);
    *(short4*)&pwb[e] = ov;
}

// ---- stage 1: taps[r][k][c] = sum_d xpad[b, l+k, d] * cwt[k][c][d]   (bf16 out)
__global__ __launch_bounds__(256, 2) void taps_gemm(
    const __hip_bfloat16* __restrict__ xpad,
    const __hip_bfloat16* __restrict__ cwt,
    __hip_bfloat16* __restrict__ taps)
{
    __shared__ __align__(16) __hip_bfloat16 At[128 * 64];
    __shared__ __align__(16) __hip_bfloat16 Bt[128 * 64];
    const int m0 = blockIdx.x * 128;
    const int n0 = blockIdx.y * 128;
    const int ktap = blockIdx.z;
    const int tid = threadIdx.x;
    const int lane = tid & 63;
    const int wv = tid >> 6;
    const int fr = lane & 15;
    const int fq = lane >> 4;
    const int wm = (wv >> 1) * 64;
    const int wn = (wv & 1) * 64;

    const __hip_bfloat16* asrc[4];
    const __hip_bfloat16* bsrc[4];
    int ldsoff[4];
    #pragma unroll
    for (int j = 0; j < 4; ++j) {
        int p = (wv * 4 + j) * 1024 + lane * 16;  // byte offset in 16KB tile
        int row = p >> 7;                          // tile row (0..127)
        int c16 = (p >> 4) & 7;                    // 16B chunk within 128B row
        ldsoff[j] = p >> 1;                        // element offset
        int gr = m0 + row;
        int b = gr >> 9, l = gr & 511;
        asrc[j] = xpad + ((size_t)(b * LPAD + l + ktap)) * 768 + c16 * 8;
        bsrc[j] = cwt + (size_t)ktap * CWT_KSTRIDE + (size_t)(n0 + row) * 768 + c16 * 8;
    }

    f32x4 acc[4][4];
    #pragma unroll
    for (int i = 0; i < 4; ++i)
        #pragma unroll
        for (int j = 0; j < 4; ++j)
            acc[i][j] = (f32x4){0.f, 0.f, 0.f, 0.f};

    for (int kt = 0; kt < 12; ++kt) {
        const int d0 = kt * 64;
        #pragma unroll
        for (int j = 0; j < 4; ++j) {
            __builtin_amdgcn_global_load_lds(
                (const __attribute__((address_space(1))) void*)(asrc[j] + d0),
                (__attribute__((address_space(3))) void*)(At + ldsoff[j]), 16, 0, 0);
            __builtin_amdgcn_global_load_lds(
                (const __attribute__((address_space(1))) void*)(bsrc[j] + d0),
                (__attribute__((address_space(3))) void*)(Bt + ldsoff[j]), 16, 0, 0);
        }
        __syncthreads();
        #pragma unroll
        for (int kk = 0; kk < 2; ++kk) {
            bf16x8 a[4], b[4];
            #pragma unroll
            for (int fm = 0; fm < 4; ++fm)
                a[fm] = *(const bf16x8*)&At[(wm + fm * 16 + fr) * 64 + kk * 32 + fq * 8];
            #pragma unroll
            for (int fn = 0; fn < 4; ++fn)
                b[fn] = *(const bf16x8*)&Bt[(wn + fn * 16 + fr) * 64 + kk * 32 + fq * 8];
            #pragma unroll
            for (int fm = 0; fm < 4; ++fm)
                #pragma unroll
                for (int fn = 0; fn < 4; ++fn)
                    acc[fm][fn] = __builtin_amdgcn_mfma_f32_16x16x32_bf16(
                        a[fm], b[fn], acc[fm][fn], 0, 0, 0);
        }
        __syncthreads();
    }

    // epilogue: C row = fq*4 + r, col = fr  (m89-verified layout); write [r][k][c]
    #pragma unroll
    for (int fm = 0; fm < 4; ++fm) {
        int gr = m0 + wm + fm * 16 + fq * 4;
        #pragma unroll
        for (int fn = 0; fn < 4; ++fn) {
            int gc = n0 + wn + fn * 16 + fr;
            #pragma unroll
            for (int r = 0; r < 4; ++r) {
                taps[((size_t)(gr + r) * W_TAPS + ktap) * 768 + gc] =
                    __float2bfloat16(acc[fm][fn][r]);
            }
        }
    }
}

// ---- cumsum over k + relu, in place on taps[r][k][c] (thread owns (r, c8) strip)
__global__ void cumsum_relu(__hip_bfloat16* __restrict__ taps) {
    int t = blockIdx.x * 256 + threadIdx.x;   // 393,216 exact
    int r = t / 96;
    int c8 = (t % 96) * 8;
    __hip_bfloat16* p = taps + (size_t)r * (W_TAPS * 768) + c8;
    float run[8];
    #pragma unroll
    for (int j = 0; j < 8; ++j) run[j] = 0.f;
    for (int k = 0; k < 12; ++k) {
        bf16x8 v = *(bf16x8*)(p + (size_t)k * 768);
        bf16x8 o;
        #pragma unroll
        for (int j = 0; j < 8; ++j) {
            run[j] += bf2f(v[j]);
            o[j] = f2bf(fmaxf(run[j], 0.f));
        }
        *(bf16x8*)(p + (size_t)k * 768) = o;
    }
}

// ---- stage 2: out[m][o] = sum_d h[m][d] * pw[o][d] + pb[o]   (fp32 out)
__global__ __launch_bounds__(256, 2) void proj_gemm(
    const __hip_bfloat16* __restrict__ h,
    const __hip_bfloat16* __restrict__ pw,
    const float* __restrict__ pb,
    float* __restrict__ out)
{
    __shared__ __align__(16) __hip_bfloat16 At[128 * 64];
    __shared__ __align__(16) __hip_bfloat16 Bt[128 * 64];
    const int m0 = blockIdx.x * 128;
    const int n0 = blockIdx.y * 128;
    const int tid = threadIdx.x;
    const int lane = tid & 63;
    const int wv = tid >> 6;
    const int fr = lane & 15;
    const int fq = lane >> 4;
    const int wm = (wv >> 1) * 64;
    const int wn = (wv & 1) * 64;

    const __hip_bfloat16* asrc[4];
    const __hip_bfloat16* bsrc[4];
    int ldsoff[4];
    #pragma unroll
    for (int j = 0; j < 4; ++j) {
        int p = (wv * 4 + j) * 1024 + lane * 16;
        int row = p >> 7;
        int c16 = (p >> 4) & 7;
        ldsoff[j] = p >> 1;
        asrc[j] = h + (size_t)(m0 + row) * 768 + c16 * 8;
        bsrc[j] = pw + (size_t)(n0 + row) * 768 + c16 * 8;
    }

    f32x4 acc[4][4];
    #pragma unroll
    for (int i = 0; i < 4; ++i)
        #pragma unroll
        for (int j = 0; j < 4; ++j)
            acc[i][j] = (f32x4){0.f, 0.f, 0.f, 0.f};

    for (int kt = 0; kt < 12; ++kt) {
        const int d0 = kt * 64;
        #pragma unroll
        for (int j = 0; j < 4; ++j) {
            __builtin_amdgcn_global_load_lds(
                (const __attribute__((address_space(1))) void*)(asrc[j] + d0),
                (__attribute__((address_space(3))) void*)(At + ldsoff[j]), 16, 0, 0);
            __builtin_amdgcn_global_load_lds(
                (const __attribute__((address_space(1))) void*)(bsrc[j] + d0),
                (__attribute__((address_space(3))) void*)(Bt + ldsoff[j]), 16, 0, 0);
        }
        __syncthreads();
        #pragma unroll
        for (int kk = 0; kk < 2; ++kk) {
            bf16x8 a[4], b[4];
            #pragma unroll
            for (int fm = 0; fm < 4; ++fm)
                a[fm] = *(const bf16x8*)&At[(wm + fm * 16 + fr) * 64 + kk * 32 + fq * 8];
            #pragma unroll
            for (int fn = 0; fn < 4; ++fn)
                b[fn] = *(const bf16x8*)&Bt[(wn + fn * 16 + fr) * 64 + kk * 32 + fq * 8];
            #pragma unroll
            for (int fm = 0; fm < 4; ++fm)
                #pragma unroll
                for (int fn = 0; fn < 4; ++fn)
                    acc[fm][fn] = __builtin_amdgcn_mfma_f32_16x16x32_bf16(
                        a[fm], b[fn], acc[fm][fn], 0, 0, 0);
        }
        __syncthreads();
    }

    #pragma unroll
    for (int fm = 0; fm < 4; ++fm) {
        int gr = m0 + wm + fm * 16 + fq * 4;
        #pragma unroll
        for (int fn = 0; fn < 4; ++fn) {
            int gc = n0 + wn + fn * 16 + fr;
            float bias = pb[gc];
            #pragma unroll
            for (int r = 0; r < 4; ++r) {
                out[(size_t)(gr + r) * 768 + gc] = acc[fm][fn][r] + bias;
            }
        }
    }
}

extern "C" void kernel_launch(void* const* d_in, const int* in_sizes, int n_in,
                              void* d_out, int out_size, void* d_ws, size_t ws_size,
                              hipStream_t stream) {
    const float* x  = (const float*)d_in[0];
    const float* cw = (const float*)d_in[1];
    const float* pw = (const float*)d_in[2];
    const float* pb = (const float*)d_in[3];
    float* out = (float*)d_out;
    char* ws = (char*)d_ws;

    // ws layout (bytes): xpad @0 (6,426,624) | cwt @6,426,624 (14,155,776)
    //                    pwb @20,582,400 (1,179,648) | taps/h @21,762,048 (75,497,472)
    __hip_bfloat16* xpad = (__hip_bfloat16*)(ws);
    __hip_bfloat16* cwt  = (__hip_bfloat16*)(ws + 6426624);
    __hip_bfloat16* pwb  = (__hip_bfloat16*)(ws + 20582400);
    __hip_bfloat16* taps = (__hip_bfloat16*)(ws + 21762048);
    if (ws_size < 97259520u) return;   // need ~93 MB scratch

    pad_cast_x <<<3138, 256, 0, stream>>>(x, xpad);
    transpose_cw<<<9216,  64, 0, stream>>>(cw, cwt);
    cast_pw    <<<576,  256, 0, stream>>>(pw, pwb);

    taps_gemm  <<<dim3(32, 6, 12), 256, 0, stream>>>(xpad, cwt, taps);
    cumsum_relu<<<1536, 256, 0, stream>>>(taps);
    proj_gemm  <<<dim3(384, 6),    256, 0, stream>>>(taps, pwb, pb, out);
}